// Round 3
// baseline (100.410 us; speedup 1.0000x reference)
//
#include <hip/hip_runtime.h>
#include <hip/hip_fp16.h>
#include <math.h>

#define B_SZ 64
#define P_SZ 256
#define N_SZ 4096
#define NC2 32                      // n-chunks for k_mpart (chunk = 128)
#define A_ANC 0.08f
#define OMEGA_ANC 1256.6370614359172f

typedef _Float16 h2v __attribute__((ext_vector_type(2)));

__device__ __forceinline__ float fdot2f(__half2 a, __half2 b, float c) {
#if __has_builtin(__builtin_amdgcn_fdot2)
    return __builtin_amdgcn_fdot2(__builtin_bit_cast(h2v, a),
                                  __builtin_bit_cast(h2v, b), c, false);
#else
    float2 af = __half22float2(a), bf = __half22float2(b);
    return fmaf(af.x, bf.x, fmaf(af.y, bf.y, c));
#endif
}

// K_A: fused trig + partial-m GEMM.
//   - computes xi-trig tile (16p x 128n) into LDS + global XP (each element written once)
//   - computes phi-trig chunk (128n x 64b) into LDS only (16x redundant, ~0.8us)
//   - m_part[c][b][p] = sum over n-chunk c of cos(phi[b,n]-xi[p,n])
// grid (16 p-tiles, 32 n-chunks) = 512 blocks -> 2 blocks/CU, 8 waves/CU.
__global__ __launch_bounds__(256, 2) void k_mpart_fused(const float* __restrict__ phi,
                                                        const float* __restrict__ xi,
                                                        __half2* __restrict__ XPg,
                                                        float* __restrict__ m_part) {
    const int pt = blockIdx.x;          // p0 = 16*pt
    const int nc = blockIdx.y;          // n0 = 128*nc
    const int tid = threadIdx.x;
    const int b = tid & 63;
    const int g = tid >> 6;

    __shared__ __half2 xs[128][20];     // [n_l][p_l], 80B rows (16B-aligned for b128)
    __shared__ __half2 ps[128][66];     // [n_l][b], pad 64->66: write 4-way, read 2-way (free)
    __shared__ float red[4][64][17];

    const int p0 = pt * 16, n0 = nc * 128;

    // xi-trig tile: 2048 elems, 8/thread; coalesced read + coalesced XP write
    for (int idx = tid; idx < 16 * 128; idx += 256) {
        int p_l = idx >> 7, n_l = idx & 127;
        float s, c;
        __sincosf(xi[(p0 + p_l) * N_SZ + n0 + n_l], &s, &c);
        __half2 h = __floats2half2_rn(c, s);
        xs[n_l][p_l] = h;
        XPg[(p0 + p_l) * N_SZ + n0 + n_l] = h;
    }
    // phi-trig chunk: 8192 elems, 32/thread; coalesced read
    for (int idx = tid; idx < 64 * 128; idx += 256) {
        int bb = idx >> 7, n_l = idx & 127;
        float s, c;
        __sincosf(phi[bb * N_SZ + n0 + n_l], &s, &c);
        ps[n_l][bb] = __floats2half2_rn(c, s);
    }
    __syncthreads();

    float acc[16];
#pragma unroll
    for (int j = 0; j < 16; ++j) acc[j] = 0.f;

    for (int i = 0; i < 32; ++i) {
        int n_l = 4 * i + g;
        __half2 pp = ps[n_l][b];                           // lane=b, 2-way = free
        const __half2* row = &xs[n_l][0];                  // broadcast ds_read_b128 x4
#pragma unroll
        for (int j = 0; j < 16; ++j)
            acc[j] = fdot2f(row[j], pp, acc[j]);           // cos(phi-xi) accumulate
    }

#pragma unroll
    for (int j = 0; j < 16; ++j) red[g][b][j] = acc[j];
    __syncthreads();
    if (tid < 64) {
#pragma unroll
        for (int j = 0; j < 16; ++j) {
            float s = red[0][tid][j] + red[1][tid][j] + red[2][tid][j] + red[3][tid][j];
            m_part[(nc * 64 + tid) * 256 + p0 + j] = s;    // [c][b][p]
        }
    }
}

// K_W: weights[b][p] = softmax_p( sum_c m_part[c][b][p] / N ). grid 64 x 256thr (~2us).
__global__ __launch_bounds__(256) void k_weights(const float* __restrict__ m_part,
                                                 float* __restrict__ weights) {
    const int b = blockIdx.x;
    const int tid = threadIdx.x;       // = p
    const int wv = tid >> 6;
    __shared__ float sred[8];

    float msum = 0.f;
#pragma unroll 8
    for (int c = 0; c < NC2; ++c)
        msum += m_part[(c * 64 + b) * 256 + tid];          // coalesced
    float logit = msum * (1.0f / 4096.0f);                 // BETA=1

    float v = logit;
    for (int o = 32; o > 0; o >>= 1) v = fmaxf(v, __shfl_xor(v, o));
    if ((tid & 63) == 0) sred[wv] = v;
    __syncthreads();
    float mx = fmaxf(fmaxf(sred[0], sred[1]), fmaxf(sred[2], sred[3]));
    float e = __expf(logit - mx);
    v = e;
    for (int o = 32; o > 0; o >>= 1) v += __shfl_xor(v, o);
    if ((tid & 63) == 0) sred[4 + wv] = v;
    __syncthreads();
    float s = sred[4] + sred[5] + sred[6] + sred[7];
    weights[b * 256 + tid] = e / s;
}

// K_B: coupling + anchor. grid (16 b-tiles of 4, 32 n-chunks of 128) = 512 blocks.
// wave = one b; each lane owns 2 consecutive n (dwordx2 loads). Weights read as
// wave-uniform float4 per 4-p group. fmaf(w, half2float(h)) -> v_fma_mix_f32.
__global__ __launch_bounds__(256, 2) void k_coupling(const __half2* __restrict__ XP,
                                                     const float* __restrict__ weights,
                                                     const float* __restrict__ phi,
                                                     const float* __restrict__ t_ptr,
                                                     float* __restrict__ out) {
    const int bt = blockIdx.x;   // 0..15
    const int nc = blockIdx.y;   // 0..31
    const int tid = threadIdx.x;
    const int b_l = tid >> 6;    // wave id = local b
    const int lane = tid & 63;

    __shared__ float wsh[4][256];
    for (int idx = tid; idx < 4 * 256; idx += 256) {
        int bb = idx >> 8, p = idx & 255;
        wsh[bb][p] = weights[(bt * 4 + bb) * 256 + p];     // coalesced
    }
    __syncthreads();

    const int n = nc * 128 + 2 * lane;                     // this lane's first n
    const __half2* col = XP + n;
    float aC0 = 0.f, aS0 = 0.f, aC1 = 0.f, aS1 = 0.f;

#pragma unroll 2
    for (int p = 0; p < 256; p += 4) {
        float4 w4 = *(const float4*)&wsh[b_l][p];          // ds_read_b128, wave-uniform
        const float w[4] = {w4.x, w4.y, w4.z, w4.w};
#pragma unroll
        for (int k = 0; k < 4; ++k) {
            uint2 v = *(const uint2*)&col[(p + k) * N_SZ]; // 8B/lane coalesced
            __half2 h0 = __builtin_bit_cast(__half2, v.x); // n
            __half2 h1 = __builtin_bit_cast(__half2, v.y); // n+1
            aC0 = fmaf(w[k], __low2float(h0), aC0);        // v_fma_mix candidates
            aS0 = fmaf(w[k], __high2float(h0), aS0);
            aC1 = fmaf(w[k], __low2float(h1), aC1);
            aS1 = fmaf(w[k], __high2float(h1), aS1);
        }
    }

    const int b = bt * 4 + b_l;
    const float wt = OMEGA_ANC * t_ptr[0];
    float2 ph2 = *(const float2*)&phi[b * N_SZ + n];
    float s0, c0, s1, c1;
    sincosf(ph2.x, &s0, &c0);
    sincosf(ph2.y, &s1, &c1);
    float2 o;
    o.x = fmaf(A_ANC, sinf(wt - ph2.x), s0 * aC0 - c0 * aS0);
    o.y = fmaf(A_ANC, sinf(wt - ph2.y), s1 * aC1 - c1 * aS1);
    *(float2*)&out[b * N_SZ + n] = o;
}

extern "C" void kernel_launch(void* const* d_in, const int* in_sizes, int n_in,
                              void* d_out, int out_size, void* d_ws, size_t ws_size,
                              hipStream_t stream) {
    const float* t   = (const float*)d_in[0];
    const float* phi = (const float*)d_in[1];
    const float* xi  = (const float*)d_in[2];
    float* out = (float*)d_out;

    char* w = (char*)d_ws;
    __half2* XP    = (__half2*)w;                          // P*N half2    = 4 MB
    float* m_part  = (float*)(w + 4u * 1024 * 1024);       // 32*64*256 f32 = 2 MB
    float* weights = (float*)(w + 6u * 1024 * 1024);       // 64*256 f32   = 64 KB

    k_mpart_fused<<<dim3(16, NC2), 256, 0, stream>>>(phi, xi, XP, m_part);
    k_weights<<<64, 256, 0, stream>>>(m_part, weights);
    k_coupling<<<dim3(16, NC2), 256, 0, stream>>>(XP, weights, phi, t, out);
}

// Round 4
// 90.022 us; speedup vs baseline: 1.1154x; 1.1154x over previous
//
#include <hip/hip_runtime.h>
#include <hip/hip_fp16.h>
#include <math.h>

#define B_SZ 64
#define P_SZ 256
#define N_SZ 4096
#define NCA 64                      // n-chunks for k_mpart (chunk = 64)
#define A_ANC 0.08f
#define OMEGA_ANC 1256.6370614359172f

typedef _Float16 h2v __attribute__((ext_vector_type(2)));

__device__ __forceinline__ float fdot2f(__half2 a, __half2 b, float c) {
#if __has_builtin(__builtin_amdgcn_fdot2)
    return __builtin_amdgcn_fdot2(__builtin_bit_cast(h2v, a),
                                  __builtin_bit_cast(h2v, b), c, false);
#else
    float2 af = __half22float2(a), bf = __half22float2(b);
    return fmaf(af.x, bf.x, fmaf(af.y, bf.y, c));
#endif
}

// K_A: fused trig + partial-m GEMM, no cross-wave reduction.
//   wave g owns p-group [p0+4g, p0+4g+3]; lane = b. 1024 blocks, 4/CU, LDS 22 KB.
//   m_part[c][b][p] = sum over 64-wide n-chunk c of cos(phi[b,n]-xi[p,n])
__global__ __launch_bounds__(256, 4) void k_mpart_fused(const float* __restrict__ phi,
                                                        const float* __restrict__ xi,
                                                        __half2* __restrict__ XPg,
                                                        float* __restrict__ m_part) {
    const int pt = blockIdx.x;          // p0 = 16*pt
    const int nc = blockIdx.y;          // n0 = 64*nc
    const int tid = threadIdx.x;
    const int b = tid & 63;
    const int g = tid >> 6;

    __shared__ __half2 xs[64][20];      // [n_l][p_l]; 80B rows (16B-aligned for b128)
    __shared__ __half2 ps[64][66];      // [n_l][b]; read 2-way = free

    const int p0 = pt * 16, n0 = nc * 64;

    // xi-trig tile (16p x 64n): 4/thread; coalesced read + coalesced XP write
#pragma unroll
    for (int k = 0; k < 4; ++k) {
        int idx = tid + k * 256;
        int p_l = idx >> 6, n_l = idx & 63;
        float s, c;
        __sincosf(xi[(p0 + p_l) * N_SZ + n0 + n_l], &s, &c);
        __half2 h = __floats2half2_rn(c, s);
        xs[n_l][p_l] = h;
        XPg[(p0 + p_l) * N_SZ + n0 + n_l] = h;
    }
    // phi-trig chunk (64b x 64n): 16/thread; coalesced read
#pragma unroll 4
    for (int k = 0; k < 16; ++k) {
        int idx = tid + k * 256;
        int bb = idx >> 6, n_l = idx & 63;
        float s, c;
        __sincosf(phi[bb * N_SZ + n0 + n_l], &s, &c);
        ps[n_l][bb] = __floats2half2_rn(c, s);
    }
    __syncthreads();

    float4 acc = {0.f, 0.f, 0.f, 0.f};
#pragma unroll 8
    for (int n_l = 0; n_l < 64; ++n_l) {
        __half2 pp = ps[n_l][b];                   // lane=b: 2-way, free
        const __half2* row = &xs[n_l][g * 4];      // wave-uniform b128 broadcast
        acc.x = fdot2f(row[0], pp, acc.x);
        acc.y = fdot2f(row[1], pp, acc.y);
        acc.z = fdot2f(row[2], pp, acc.z);
        acc.w = fdot2f(row[3], pp, acc.w);
    }
    // thread (b,g) owns p0+4g..+3 for batch b: one float4 store
    *(float4*)&m_part[(nc * 64 + b) * 256 + p0 + 4 * g] = acc;
}

// K_W: weights[b][p] = softmax_p( sum_c m_part[c][b][p] / N ). grid 64 x 256thr.
__global__ __launch_bounds__(256) void k_weights(const float* __restrict__ m_part,
                                                 float* __restrict__ weights) {
    const int b = blockIdx.x;
    const int tid = threadIdx.x;       // = p
    const int wv = tid >> 6;
    __shared__ float sred[8];

    float msum = 0.f;
#pragma unroll 8
    for (int c = 0; c < NCA; ++c)
        msum += m_part[(c * 64 + b) * 256 + tid];          // coalesced
    float logit = msum * (1.0f / 4096.0f);                 // BETA=1

    float v = logit;
    for (int o = 32; o > 0; o >>= 1) v = fmaxf(v, __shfl_xor(v, o));
    if ((tid & 63) == 0) sred[wv] = v;
    __syncthreads();
    float mx = fmaxf(fmaxf(sred[0], sred[1]), fmaxf(sred[2], sred[3]));
    float e = __expf(logit - mx);
    v = e;
    for (int o = 32; o > 0; o >>= 1) v += __shfl_xor(v, o);
    if ((tid & 63) == 0) sred[4 + wv] = v;
    __syncthreads();
    float s = sred[4] + sred[5] + sred[6] + sred[7];
    weights[b * 256 + tid] = e / s;
}

// K_B: coupling + anchor. grid (16 b-tiles of 4, 32 n-chunks of 128) = 512 blocks.
// wave = one b; lane owns 2 consecutive n (dwordx2). float4 weight broadcast.
__global__ __launch_bounds__(256, 2) void k_coupling(const __half2* __restrict__ XP,
                                                     const float* __restrict__ weights,
                                                     const float* __restrict__ phi,
                                                     const float* __restrict__ t_ptr,
                                                     float* __restrict__ out) {
    const int bt = blockIdx.x;   // 0..15
    const int nc = blockIdx.y;   // 0..31
    const int tid = threadIdx.x;
    const int b_l = tid >> 6;    // wave id = local b
    const int lane = tid & 63;

    __shared__ float wsh[4][256];
    for (int idx = tid; idx < 4 * 256; idx += 256) {
        int bb = idx >> 8, p = idx & 255;
        wsh[bb][p] = weights[(bt * 4 + bb) * 256 + p];     // coalesced
    }
    __syncthreads();

    const int n = nc * 128 + 2 * lane;                     // this lane's first n
    const __half2* col = XP + n;
    float aC0 = 0.f, aS0 = 0.f, aC1 = 0.f, aS1 = 0.f;

#pragma unroll 2
    for (int p = 0; p < 256; p += 4) {
        float4 w4 = *(const float4*)&wsh[b_l][p];          // ds_read_b128, wave-uniform
        const float w[4] = {w4.x, w4.y, w4.z, w4.w};
#pragma unroll
        for (int k = 0; k < 4; ++k) {
            uint2 v = *(const uint2*)&col[(p + k) * N_SZ]; // 8B/lane coalesced
            __half2 h0 = __builtin_bit_cast(__half2, v.x); // n
            __half2 h1 = __builtin_bit_cast(__half2, v.y); // n+1
            aC0 = fmaf(w[k], __low2float(h0), aC0);        // v_fma_mix candidates
            aS0 = fmaf(w[k], __high2float(h0), aS0);
            aC1 = fmaf(w[k], __low2float(h1), aC1);
            aS1 = fmaf(w[k], __high2float(h1), aS1);
        }
    }

    const int b = bt * 4 + b_l;
    const float wt = OMEGA_ANC * t_ptr[0];
    float2 ph2 = *(const float2*)&phi[b * N_SZ + n];
    float s0, c0, s1, c1;
    __sincosf(ph2.x, &s0, &c0);                            // fast-path: err ~1e-6 << margin
    __sincosf(ph2.y, &s1, &c1);
    float2 o;
    o.x = fmaf(A_ANC, __sinf(wt - ph2.x), s0 * aC0 - c0 * aS0);
    o.y = fmaf(A_ANC, __sinf(wt - ph2.y), s1 * aC1 - c1 * aS1);
    *(float2*)&out[b * N_SZ + n] = o;
}

extern "C" void kernel_launch(void* const* d_in, const int* in_sizes, int n_in,
                              void* d_out, int out_size, void* d_ws, size_t ws_size,
                              hipStream_t stream) {
    const float* t   = (const float*)d_in[0];
    const float* phi = (const float*)d_in[1];
    const float* xi  = (const float*)d_in[2];
    float* out = (float*)d_out;

    char* w = (char*)d_ws;
    __half2* XP    = (__half2*)w;                          // P*N half2      = 4 MB
    float* m_part  = (float*)(w + 4u * 1024 * 1024);       // 64*64*256 f32  = 4 MB
    float* weights = (float*)(w + 8u * 1024 * 1024);       // 64*256 f32     = 64 KB

    k_mpart_fused<<<dim3(16, NCA), 256, 0, stream>>>(phi, xi, XP, m_part);
    k_weights<<<64, 256, 0, stream>>>(m_part, weights);
    k_coupling<<<dim3(16, 32), 256, 0, stream>>>(XP, weights, phi, t, out);
}